// Round 4
// baseline (7496.764 us; speedup 1.0000x reference)
//
#include <hip/hip_runtime.h>

#define B_ 128
#define T_ 2048
#define NITER (T_ + 4)   // i = 0 .. T_+3

__device__ __forceinline__ float fast_sigmoid(float x){ return 1.0f/(1.0f+__expf(-x)); }
__device__ __forceinline__ float fast_tanh(float x){
    float a=fabsf(x); float e=__expf(2.0f*a); float r=1.0f-2.0f/(e+1.0f);
    return (x<0.0f)?-r:r;
}
// Barrier draining only LDS (lgkmcnt): all inter-thread comms are LDS; global
// loads/stores may stay in flight (compiler still guards reg uses with vmcnt).
__device__ __forceinline__ void lds_barrier(){
    asm volatile("s_waitcnt lgkmcnt(0)\n\ts_barrier" ::: "memory");
}
__device__ __forceinline__ void lds_fence(){
    asm volatile("s_waitcnt lgkmcnt(0)" ::: "memory");
}

// One workgroup per batch element. 8 waves:
//  waves 0-3: LSTM, intra-wave (4 lanes per h-element, gate gather via shfl)
//  wave  4  : transition tail (z-chain), fully intra-wave
//  wave  5  : obs prefetch (lanes 0-31) + one-time const build
//  waves 6,7: hpart + LN-partials for trans (1 iter ahead) + fused decoder
__global__ __launch_bounds__(512) void fused_kernel(
    const float* __restrict__ obs,
    const float* __restrict__ Wih,  const float* __restrict__ Whh,
    const float* __restrict__ bih,  const float* __restrict__ bhh,
    const float* __restrict__ tw1,  const float* __restrict__ tb1,
    const float* __restrict__ tg,   const float* __restrict__ tbeta,
    const float* __restrict__ tw2,  const float* __restrict__ tb2,
    const float* __restrict__ tw3,  const float* __restrict__ tb3,
    const float* __restrict__ ow1,  const float* __restrict__ ob1,
    const float* __restrict__ og,   const float* __restrict__ obeta,
    const float* __restrict__ ow2,  const float* __restrict__ ob2,
    const float* __restrict__ ow3,  const float* __restrict__ ob3,
    const float* __restrict__ z0m,  const float* __restrict__ z0lv,
    float* __restrict__ out_om,  float* __restrict__ out_olv,
    float* __restrict__ out_tm,  float* __restrict__ out_tlv)
{
    __shared__ __align__(16) float comb_s[2][64];   // h double-buffer
    __shared__ __align__(16) float obs_s[2][32];
    __shared__ __align__(16) float hp_s[2][128];    // trans h-part (b1 folded in)
    __shared__ __align__(16) float scal_s[2][16];   // [w*7+ {S,S2,v0..v4}]
    __shared__ __align__(16) float h1_s[128];
    __shared__ __align__(16) float h2_s[64];
    __shared__ __align__(16) float tm_s[2][8];
    __shared__ __align__(16) float tc_s[32];        // M_t[25], cs_t[5] @25
    __shared__ __align__(16) float oc_s[40];        // M_o[25], cs_o@25, vb_o@30, Sb@35, Sb2@36
    __shared__ __align__(16) float w1d[640];
    __shared__ float ob1d[128], ogd[128], obed[128];
    __shared__ __align__(16) float w2d[8320];       // [k*65+j] = ow2[j*128+k]
    __shared__ float ob2d[64];
    __shared__ __align__(16) float w3d[4160];       // [k*65+j] = ow3[j*64+k]
    __shared__ float ob3d[64];
    __shared__ __align__(16) float dech1[2][128];
    __shared__ __align__(16) float dech2[2][64];

    const int tid  = threadIdx.x;
    const int b    = blockIdx.x;
    const int wave = tid >> 6;
    const int lane = tid & 63;

    // Unioned per-role weight registers:
    //  LSTM : [0..31] Wih row, [32..95] Whh row
    //  w4   : [0..127] t_w2 row, [128..143] t_w3 chunk, [144..148] Wz row a, [149..153] Wz row b
    //  w6/7 : [0..63] t_w1 h-cols row, [64..68] Wz row
    float wr[154];
    #pragma unroll
    for (int k = 0; k < 154; k++) wr[k] = 0.f;
    float f0=0.f, f1=0.f, f2=0.f, f3=0.f, f4=0.f, f5=0.f;
    float z0v=0.f, z1v=0.f, z2v=0.f, z3v=0.f, z4v=0.f;   // w4: z state
    float c_st = 0.f;                                    // LSTM: cell state
    float carry = 0.f;                                   // w5: obs prefetch

    if (wave < 4) {
        const int j = tid >> 2, p = tid & 3;
        const int r = p*64 + j;
        f0 = bih[r] + bhh[r];
        #pragma unroll
        for (int k = 0; k < 32; k++) wr[k]      = Wih[r*32 + k];
        #pragma unroll
        for (int k = 0; k < 64; k++) wr[32 + k] = Whh[r*64 + k];
    } else if (wave == 4) {
        #pragma unroll
        for (int k = 0; k < 128; k++) wr[k] = tw2[lane*128 + k];
        if (lane < 40) {
            const int j3 = lane >> 2, pp = lane & 3;
            #pragma unroll
            for (int k = 0; k < 16; k++) wr[128 + k] = tw3[j3*64 + pp*16 + k];
            f5 = tb3[j3];
        }
        #pragma unroll
        for (int c = 0; c < 5; c++) wr[144 + c] = tw1[lane*69 + 64 + c];
        #pragma unroll
        for (int c = 0; c < 5; c++) wr[149 + c] = tw1[(lane+64)*69 + 64 + c];
        f0 = tg[lane]; f1 = tbeta[lane]; f2 = tg[lane+64]; f3 = tbeta[lane+64];
        f4 = tb2[lane];
        z0v = z0m[0]; z1v = z0m[1]; z2v = z0m[2]; z3v = z0m[3]; z4v = z0m[4];
    } else if (wave == 5) {
        if (lane < 32) {
            obs_s[0][lane] = obs[(size_t)b*T_*32 + lane];
            carry          = obs[(size_t)b*T_*32 + 32 + lane];
        }
        // one-time decoder LN constants
        if (lane < 25) {
            const int a = lane/5, c = lane%5; float s = 0.f;
            for (int j = 0; j < 128; j++) s += ow1[j*5+a]*ow1[j*5+c];
            oc_s[lane] = s;
        } else if (lane < 30) {
            const int c = lane-25; float s = 0.f;
            for (int j = 0; j < 128; j++) s += ow1[j*5+c];
            oc_s[25+c] = s;
        } else if (lane < 35) {
            const int c = lane-30; float s = 0.f;
            for (int j = 0; j < 128; j++) s += ob1[j]*ow1[j*5+c];
            oc_s[30+c] = s;
        } else if (lane == 35) {
            float s = 0.f;
            for (int j = 0; j < 128; j++) s += ob1[j];
            oc_s[35] = s;
        } else if (lane == 36) {
            float s = 0.f;
            for (int j = 0; j < 128; j++) s += ob1[j]*ob1[j];
            oc_s[36] = s;
        }
    } else {            // waves 6,7
        const int jr = (wave == 6) ? lane : lane + 64;
        #pragma unroll
        for (int k = 0; k < 64; k++) wr[k] = tw1[jr*69 + k];
        #pragma unroll
        for (int c = 0; c < 5; c++)  wr[64+c] = tw1[jr*69 + 64 + c];
        f0 = tb1[jr];
        if (wave == 6) {           // one-time trans LN constants
            if (lane < 25) {
                const int a = lane/5, c = lane%5; float s = 0.f;
                for (int j = 0; j < 128; j++) s += tw1[j*69+64+a]*tw1[j*69+64+c];
                tc_s[lane] = s;
            } else if (lane < 30) {
                const int c = lane-25; float s = 0.f;
                for (int j = 0; j < 128; j++) s += tw1[j*69+64+c];
                tc_s[25+c] = s;
            }
        }
    }

    // decoder weights -> LDS (all threads)
    for (int idx = tid; idx < 640;  idx += 512) w1d[idx] = ow1[idx];
    for (int idx = tid; idx < 128;  idx += 512) {
        ob1d[idx] = ob1[idx]; ogd[idx] = og[idx]; obed[idx] = obeta[idx];
    }
    for (int idx = tid; idx < 8192; idx += 512) {
        const int k = idx >> 6, j = idx & 63;
        w2d[k*65 + j] = ow2[j*128 + k];
    }
    for (int idx = tid; idx < 4096; idx += 512) {
        const int k = idx >> 6, j = idx & 63;
        w3d[k*65 + j] = ow3[j*64 + k];
    }
    for (int idx = tid; idx < 64; idx += 512) { ob2d[idx] = ob2[idx]; ob3d[idx] = ob3[idx]; }

    if (tid < 64) { comb_s[0][tid] = 0.f; comb_s[1][tid] = 0.f; }
    if (tid < 5) {
        tm_s[0][tid] = z0m[tid]; tm_s[1][tid] = 0.f;
        out_tm [(size_t)b*T_*5 + tid] = z0m[tid];
        out_tlv[(size_t)b*T_*5 + tid] = z0lv[tid];
    }
    __syncthreads();

    for (int i = 0; i < NITER; ++i) {
        const int cur = i & 1, prev = cur ^ 1;

        if (wave < 4) {
            if (i < T_) {
                const int j = tid >> 2, p = tid & 3;
                float acc0 = f0, acc1 = 0.f;
                const float4* ob4 = (const float4*)obs_s[cur];
                #pragma unroll
                for (int k4 = 0; k4 < 8; k4++) {
                    float4 o = ob4[k4];
                    acc0 += wr[k4*4+0]*o.x + wr[k4*4+2]*o.z;
                    acc1 += wr[k4*4+1]*o.y + wr[k4*4+3]*o.w;
                }
                const float4* hb4 = (const float4*)comb_s[prev];
                #pragma unroll
                for (int k4 = 0; k4 < 16; k4++) {
                    float4 h = hb4[k4];
                    acc0 += wr[32+k4*4+0]*h.x + wr[32+k4*4+2]*h.z;
                    acc1 += wr[32+k4*4+1]*h.y + wr[32+k4*4+3]*h.w;
                }
                const float own = acc0 + acc1;
                const float v1 = __shfl_xor(own, 1);
                const float v2 = __shfl_xor(own, 2);
                const float v3 = __shfl_xor(v1, 2);
                // lane p holds values from source-p: own=p, v1=p^1, v2=p^2, v3=p^3
                const float gi = (p==0)?own:((p==1)?v1:((p==2)?v2:v3));
                const float gf = (p==1)?own:((p==0)?v1:((p==3)?v2:v3));
                const float gg = (p==2)?own:((p==3)?v1:((p==0)?v2:v3));
                const float go = (p==3)?own:((p==2)?v1:((p==1)?v2:v3));
                const float iv = fast_sigmoid(gi), fv = fast_sigmoid(gf);
                const float gv = fast_tanh(gg),    ov = fast_sigmoid(go);
                c_st = fv*c_st + iv*gv;
                const float hval = ov * fast_tanh(c_st);
                if (p == 0) comb_s[cur][j] = hval;
            }
        } else if (wave == 4) {
            if (i >= 3 && i <= T_+1) {           // trans step tau = i-2 in [1, T-1]
                const int slot = i & 1;          // == tau & 1
                const float hpa = hp_s[slot][lane];
                const float hpb = hp_s[slot][lane+64];
                const float S   = scal_s[slot][0] + scal_s[slot][7];
                const float S2  = scal_s[slot][1] + scal_s[slot][8];
                const float v0  = scal_s[slot][2] + scal_s[slot][9];
                const float v1p = scal_s[slot][3] + scal_s[slot][10];
                const float v2p = scal_s[slot][4] + scal_s[slot][11];
                const float v3p = scal_s[slot][5] + scal_s[slot][12];
                const float v4p = scal_s[slot][6] + scal_s[slot][13];
                const float zca = wr[144]*z0v + wr[145]*z1v + wr[146]*z2v + wr[147]*z3v + wr[148]*z4v;
                const float zcb = wr[149]*z0v + wr[150]*z1v + wr[151]*z2v + wr[152]*z3v + wr[153]*z4v;
                const float csz = tc_s[25]*z0v + tc_s[26]*z1v + tc_s[27]*z2v + tc_s[28]*z3v + tc_s[29]*z4v;
                const float vz  = v0*z0v + v1p*z1v + v2p*z2v + v3p*z3v + v4p*z4v;
                const float r0 = tc_s[0]*z0v + tc_s[1]*z1v + tc_s[2]*z2v + tc_s[3]*z3v + tc_s[4]*z4v;
                const float r1 = tc_s[5]*z0v + tc_s[6]*z1v + tc_s[7]*z2v + tc_s[8]*z3v + tc_s[9]*z4v;
                const float r2 = tc_s[10]*z0v + tc_s[11]*z1v + tc_s[12]*z2v + tc_s[13]*z3v + tc_s[14]*z4v;
                const float r3 = tc_s[15]*z0v + tc_s[16]*z1v + tc_s[17]*z2v + tc_s[18]*z3v + tc_s[19]*z4v;
                const float r4 = tc_s[20]*z0v + tc_s[21]*z1v + tc_s[22]*z2v + tc_s[23]*z3v + tc_s[24]*z4v;
                const float zMz = r0*z0v + r1*z1v + r2*z2v + r3*z3v + r4*z4v;
                const float Sa  = S + csz;
                const float Sa2 = S2 + 2.f*vz + zMz;
                const float mean = Sa * (1.0f/128.0f);
                const float var  = fmaxf(Sa2*(1.0f/128.0f) - mean*mean, 0.0f);
                const float rs   = rsqrtf(var + 1e-5f);
                const float h1a = fast_tanh((hpa + zca - mean)*rs*f0 + f1);
                const float h1b = fast_tanh((hpb + zcb - mean)*rs*f2 + f3);
                h1_s[lane] = h1a; h1_s[lane+64] = h1b;
                lds_fence();
                float acc = f4;
                const float4* h14 = (const float4*)h1_s;
                #pragma unroll
                for (int kk = 0; kk < 32; kk++) {
                    float4 h4 = h14[kk];
                    acc += wr[kk*4+0]*h4.x + wr[kk*4+1]*h4.y + wr[kk*4+2]*h4.z + wr[kk*4+3]*h4.w;
                }
                const float h2v = fast_tanh(acc);
                h2_s[lane] = h2v;
                lds_fence();
                if (lane < 40) {
                    const int pp = lane & 3;
                    float a3 = 0.f;
                    const float4* h24 = (const float4*)h2_s;
                    #pragma unroll
                    for (int c4 = 0; c4 < 4; c4++) {
                        float4 hh = h24[pp*4 + c4];
                        a3 += wr[128+c4*4+0]*hh.x + wr[128+c4*4+1]*hh.y
                            + wr[128+c4*4+2]*hh.z + wr[128+c4*4+3]*hh.w;
                    }
                    a3 += __shfl_xor(a3, 1);
                    a3 += __shfl_xor(a3, 2);
                    if (pp == 0) {
                        const int j3 = lane >> 2;
                        const float val = f5 + a3;
                        const int tau = i - 2;
                        const size_t row = (size_t)b*T_ + tau;
                        if (j3 < 5) { tm_s[slot][j3] = val; out_tm[row*5 + j3] = val; }
                        else        out_tlv[row*5 + (j3-5)] = fminf(10.0f, fmaxf(-10.0f, val));
                    }
                }
                lds_fence();
                z0v = tm_s[slot][0]; z1v = tm_s[slot][1]; z2v = tm_s[slot][2];
                z3v = tm_s[slot][3]; z4v = tm_s[slot][4];
            }
        } else if (wave == 5) {
            if (lane < 32) {
                const int t_w = i + 1, t_l = i + 2;
                if (t_w < T_) obs_s[t_w & 1][lane] = carry;
                if (t_l < T_) carry = obs[((size_t)b*T_ + t_l)*32 + lane];
            }
        } else {                                   // waves 6, 7
            const int w = wave - 6;
            const int tauh = i - 1;                // h-part for trans step tauh
            if (tauh >= 1 && tauh <= T_-1) {
                const int slot = tauh & 1;
                float a0 = f0, a1 = 0.f;
                const float4* hb4 = (const float4*)comb_s[prev];
                #pragma unroll
                for (int k4 = 0; k4 < 16; k4++) {
                    float4 h = hb4[k4];
                    a0 += wr[k4*4+0]*h.x + wr[k4*4+2]*h.z;
                    a1 += wr[k4*4+1]*h.y + wr[k4*4+3]*h.w;
                }
                const float hp = a0 + a1;
                hp_s[slot][w*64 + lane] = hp;
                float s = hp, s2 = hp*hp;
                float p0 = hp*wr[64], p1 = hp*wr[65], p2 = hp*wr[66], p3 = hp*wr[67], p4 = hp*wr[68];
                #pragma unroll
                for (int m = 1; m < 64; m <<= 1) {
                    s  += __shfl_xor(s,  m);
                    s2 += __shfl_xor(s2, m);
                    p0 += __shfl_xor(p0, m);
                    p1 += __shfl_xor(p1, m);
                    p2 += __shfl_xor(p2, m);
                    p3 += __shfl_xor(p3, m);
                    p4 += __shfl_xor(p4, m);
                }
                if (lane == 0) {
                    float* d = &scal_s[slot][w*7];
                    d[0]=s; d[1]=s2; d[2]=p0; d[3]=p1; d[4]=p2; d[5]=p3; d[6]=p4;
                }
            }
            // fused decoder: w6 handles even rows, w7 odd rows; A then B on alternate iters
            const bool doA = ((i & 1) == (w == 0 ? 1 : 0));
            if (doA) {
                const int tauA = i - 3;
                if (tauA >= 0 && tauA <= T_-1) {
                    const int ds_ = tauA & 1;
                    const float t0 = tm_s[ds_][0], t1 = tm_s[ds_][1], t2 = tm_s[ds_][2];
                    const float t3 = tm_s[ds_][3], t4 = tm_s[ds_][4];
                    const float Sa = oc_s[35] + oc_s[25]*t0 + oc_s[26]*t1 + oc_s[27]*t2
                                   + oc_s[28]*t3 + oc_s[29]*t4;
                    const float vz = oc_s[30]*t0 + oc_s[31]*t1 + oc_s[32]*t2 + oc_s[33]*t3 + oc_s[34]*t4;
                    const float q0 = oc_s[0]*t0 + oc_s[1]*t1 + oc_s[2]*t2 + oc_s[3]*t3 + oc_s[4]*t4;
                    const float q1 = oc_s[5]*t0 + oc_s[6]*t1 + oc_s[7]*t2 + oc_s[8]*t3 + oc_s[9]*t4;
                    const float q2 = oc_s[10]*t0 + oc_s[11]*t1 + oc_s[12]*t2 + oc_s[13]*t3 + oc_s[14]*t4;
                    const float q3 = oc_s[15]*t0 + oc_s[16]*t1 + oc_s[17]*t2 + oc_s[18]*t3 + oc_s[19]*t4;
                    const float q4 = oc_s[20]*t0 + oc_s[21]*t1 + oc_s[22]*t2 + oc_s[23]*t3 + oc_s[24]*t4;
                    const float zMz = q0*t0 + q1*t1 + q2*t2 + q3*t3 + q4*t4;
                    const float Sa2 = oc_s[36] + 2.f*vz + zMz;
                    const float mean = Sa * (1.0f/128.0f);
                    const float var  = fmaxf(Sa2*(1.0f/128.0f) - mean*mean, 0.0f);
                    const float rs   = rsqrtf(var + 1e-5f);
                    const int j0 = lane, j1 = lane + 64;
                    const float aa = ob1d[j0] + w1d[j0*5+0]*t0 + w1d[j0*5+1]*t1 + w1d[j0*5+2]*t2
                                   + w1d[j0*5+3]*t3 + w1d[j0*5+4]*t4;
                    const float ab = ob1d[j1] + w1d[j1*5+0]*t0 + w1d[j1*5+1]*t1 + w1d[j1*5+2]*t2
                                   + w1d[j1*5+3]*t3 + w1d[j1*5+4]*t4;
                    dech1[w][j0] = fast_tanh((aa - mean)*rs*ogd[j0] + obed[j0]);
                    dech1[w][j1] = fast_tanh((ab - mean)*rs*ogd[j1] + obed[j1]);
                }
            } else {
                const int tauB = i - 4;
                if (tauB >= 0 && tauB <= T_-1) {
                    float acc = ob2d[lane];
                    const float4* h14 = (const float4*)dech1[w];
                    #pragma unroll 8
                    for (int kk = 0; kk < 32; kk++) {
                        float4 h4 = h14[kk];
                        acc += w2d[(4*kk+0)*65 + lane]*h4.x + w2d[(4*kk+1)*65 + lane]*h4.y
                             + w2d[(4*kk+2)*65 + lane]*h4.z + w2d[(4*kk+3)*65 + lane]*h4.w;
                    }
                    const float h2v = fast_tanh(acc);
                    dech2[w][lane] = h2v;
                    lds_fence();
                    float a3 = ob3d[lane];
                    const float4* h24 = (const float4*)dech2[w];
                    #pragma unroll 4
                    for (int kk = 0; kk < 16; kk++) {
                        float4 h4 = h24[kk];
                        a3 += w3d[(4*kk+0)*65 + lane]*h4.x + w3d[(4*kk+1)*65 + lane]*h4.y
                            + w3d[(4*kk+2)*65 + lane]*h4.z + w3d[(4*kk+3)*65 + lane]*h4.w;
                    }
                    const size_t row = (size_t)b*T_ + tauB;
                    if (lane < 32) out_om[row*32 + lane] = a3;
                    else           out_olv[row*32 + (lane-32)] = fminf(10.0f, fmaxf(-10.0f, a3));
                }
            }
        }
        lds_barrier();
    }
}

extern "C" void kernel_launch(void* const* d_in, const int* in_sizes, int n_in,
                              void* d_out, int out_size, void* d_ws, size_t ws_size,
                              hipStream_t stream) {
    const float* obs  = (const float*)d_in[0];
    const float* Wih  = (const float*)d_in[1];
    const float* Whh  = (const float*)d_in[2];
    const float* bih  = (const float*)d_in[3];
    const float* bhh  = (const float*)d_in[4];
    const float* tw1  = (const float*)d_in[5];
    const float* tb1  = (const float*)d_in[6];
    const float* tg   = (const float*)d_in[7];
    const float* tbe  = (const float*)d_in[8];
    const float* tw2  = (const float*)d_in[9];
    const float* tb2  = (const float*)d_in[10];
    const float* tw3  = (const float*)d_in[11];
    const float* tb3  = (const float*)d_in[12];
    const float* ow1  = (const float*)d_in[13];
    const float* ob1  = (const float*)d_in[14];
    const float* og   = (const float*)d_in[15];
    const float* obe  = (const float*)d_in[16];
    const float* ow2  = (const float*)d_in[17];
    const float* ob2  = (const float*)d_in[18];
    const float* ow3  = (const float*)d_in[19];
    const float* ob3  = (const float*)d_in[20];
    const float* z0m  = (const float*)d_in[21];
    const float* z0lv = (const float*)d_in[22];

    float* out0 = (float*)d_out;                   // obs_means   (B,T,32)
    float* out1 = out0 + (size_t)B_*T_*32;         // obs_logvars (B,T,32)
    float* out2 = out1 + (size_t)B_*T_*32;         // trans_means (B,T,5)
    float* out3 = out2 + (size_t)B_*T_*5;          // trans_logvars

    fused_kernel<<<B_, 512, 0, stream>>>(obs, Wih, Whh, bih, bhh,
                                         tw1, tb1, tg, tbe, tw2, tb2, tw3, tb3,
                                         ow1, ob1, og, obe, ow2, ob2, ow3, ob3,
                                         z0m, z0lv, out0, out1, out2, out3);
}